// Round 7
// baseline (198.355 us; speedup 1.0000x reference)
//
#include <hip/hip_runtime.h>
#include <hip/hip_bf16.h>
#include <math.h>

#define B_ 2
#define N_ 4096
#define C_ 256
#define H_ 8
#define K_ 32
#define NP_ (B_*N_)
#define CAPW 256

typedef __attribute__((ext_vector_type(8))) short bf16x8;
typedef __attribute__((ext_vector_type(4))) float f32x4;

__device__ __forceinline__ float bf2f(unsigned short v){
    union { unsigned int u; float f; } x; x.u = ((unsigned int)v) << 16; return x.f;
}
__device__ __forceinline__ unsigned short f2bf(float f){
    union { float f; unsigned int u; } x; x.f = f;
    return (unsigned short)((x.u + 0x7FFFu + ((x.u >> 16) & 1u)) >> 16);
}
__device__ __forceinline__ unsigned int mono(float f){
    union { float f; unsigned int u; } x; x.f = f;
    return x.u ^ (0x80000000u | (unsigned int)((int)x.u >> 31));
}

// ---------------- batched weight fp32 -> bf16 into contiguous Wbase ----------------
__global__ __launch_bounds__(256) void k_cvt_all(
    const float* __restrict__ s0, const float* __restrict__ s1,
    const float* __restrict__ s2, const float* __restrict__ s3,
    const float* __restrict__ s4, const float* __restrict__ s5,
    const float* __restrict__ s6, unsigned short* __restrict__ dst)
{
    int i = blockIdx.x*256 + threadIdx.x;   // 3328*256 = 851968 exactly
    float v;
    if (i < 327680){
        int seg = i >> 16, off = i & 65535;
        const float* s = (seg==0)?s0:(seg==1)?s1:(seg==2)?s2:(seg==3)?s3:s4;
        v = s[off];
    } else if (i < 720896){
        v = s5[i - 327680];
    } else {
        v = s6[i - 720896];
    }
    dst[i] = f2bf(v);
}

// ---------------- pack xyzB -> (-2x,-2y,-2z,|p|^2) float4 ----------------
__global__ __launch_bounds__(256) void k_prep(const float* __restrict__ xyzB,
                                              f32x4* __restrict__ PB){
    int i = blockIdx.x*256 + threadIdx.x;
    if (i < NP_){
        float x = xyzB[i*3], y = xyzB[i*3+1], z = xyzB[i*3+2];
        f32x4 o;
        o[0] = -2.f*x; o[1] = -2.f*y; o[2] = -2.f*z;
        o[3] = x*x + y*y + z*z;
        PB[i] = o;
    }
}

// ---------------- fused LN(featA) + transpose -> F cols 0..255 (bf16) --------------
// 256 blocks x 32 points; tile [32][257] skewed; featA read ONCE.
__global__ __launch_bounds__(256) void k_lnt(const float* __restrict__ fa,
        const float* __restrict__ lnw, const float* __restrict__ lnb,
        unsigned short* __restrict__ F){
    __shared__ float tile[32][257];
    __shared__ float ps[8][32], pq[8][32];
    __shared__ float st[2][32];
    const int t = threadIdx.x;
    const int nx = t & 31, cy = t >> 5;
    const int pbase = blockIdx.x * 32;
    const int b = pbase >> 12, n0 = pbase & 4095;
    const float* sp = fa + (size_t)b*C_*N_ + n0;
    #pragma unroll 4
    for (int it = 0; it < 32; it++){
        int c = cy + it*8;
        tile[nx][c] = sp[(size_t)c*N_ + nx];
    }
    __syncthreads();
    {
        float s = 0.f, q = 0.f;
        #pragma unroll 8
        for (int i = 0; i < 32; i++){
            int cc = cy*32 + ((i + cy) & 31);   // skew to dodge bank aliasing
            float x = tile[nx][cc];
            s += x; q = fmaf(x, x, q);
        }
        ps[cy][nx] = s; pq[cy][nx] = q;
    }
    __syncthreads();
    if (t < 32){
        float S = 0.f, Q = 0.f;
        #pragma unroll
        for (int j = 0; j < 8; j++){ S += ps[j][t]; Q += pq[j][t]; }
        float m = S*(1.f/256.f);
        float v = Q*(1.f/256.f) - m*m;
        st[0][t] = m; st[1][t] = rsqrtf(v + 1e-5f);
    }
    __syncthreads();
    const int p = pbase + nx;
    const float m = st[0][nx], r = st[1][nx];
    #pragma unroll
    for (int j = 0; j < 4; j++){
        bf16x8 ob;
        #pragma unroll
        for (int e = 0; e < 8; e++){
            int c = cy*32 + j*8 + e;
            ob[e] = (short)f2bf((tile[nx][c]-m)*r*lnw[c] + lnb[c]);
        }
        *(bf16x8*)(F + (size_t)p*768 + cy*32 + j*8) = ob;
    }
}

// ---------------- transpose featB (B,C,N)->(B,N,C) bf16 ----------------
__global__ __launch_bounds__(256) void k_transpose(const float* __restrict__ src,
                            unsigned short* __restrict__ dst){
    __shared__ float tile[64][65];
    const int b = blockIdx.z;
    const int n0 = blockIdx.x*64, c0 = blockIdx.y*64;
    const int tx = threadIdx.x & 63, ty = threadIdx.x >> 6;
    const float* sp = src + (size_t)b*C_*N_;
    #pragma unroll
    for (int i = 0; i < 16; i++){
        int cr = ty + i*4;
        tile[cr][tx] = sp[(size_t)(c0+cr)*N_ + n0 + tx];
    }
    __syncthreads();
    const int c = c0 + tx;
    #pragma unroll
    for (int i = 0; i < 16; i++){
        int nr = ty + i*4;
        int p = (b<<12) + n0 + nr;
        dst[(size_t)p*256 + c] = f2bf(tile[tx][nr]);
    }
}

// ---------------- KNN: storage-free two-pass, one query per wave ----------------
__global__ __launch_bounds__(256) void k_knn(const float* __restrict__ xyzA,
        const f32x4* __restrict__ PB, int* __restrict__ knn){
    const int wv = threadIdx.x >> 6, lane = threadIdx.x & 63;
    const int p = blockIdx.x*4 + wv;
    const int b = p >> 12;
    const f32x4* pb = PB + ((size_t)b << 12);
    const float ax = xyzA[(size_t)p*3], ay = xyzA[(size_t)p*3+1], az = xyzA[(size_t)p*3+2];

    unsigned long long mn = ~0ull;
    #pragma unroll 8
    for (int i = 0; i < 64; i++){
        const int m = i*64 + lane;
        f32x4 c = pb[m];
        float d = fmaf(ax, c[0], fmaf(ay, c[1], fmaf(az, c[2], c[3])));
        unsigned long long key = (((unsigned long long)mono(d)) << 12) | (unsigned int)m;
        mn = key < mn ? key : mn;
    }
    unsigned int rk = 0;
    for (int j = 0; j < 64; j++){
        unsigned long long o = __shfl(mn, j, 64);
        rk += (o < mn) ? 1u : 0u;
    }
    unsigned long long sel = (rk == 31u) ? mn : ~0ull;
    #pragma unroll
    for (int off = 32; off; off >>= 1){
        unsigned long long o = __shfl_xor(sel, off, 64);
        sel = o < sel ? o : sel;
    }
    const unsigned long long v = sel;
    const unsigned int vhi = (unsigned int)(v >> 12);
    const unsigned int vlo = (unsigned int)(v & 0xFFFull);

    __shared__ unsigned long long cand[4][CAPW];
    __shared__ unsigned int cnt[4];
    if (lane == 0) cnt[wv] = 0u;
    #pragma unroll 8
    for (int i = 0; i < 64; i++){
        const int m = i*64 + lane;
        f32x4 c = pb[m];
        float d = fmaf(ax, c[0], fmaf(ay, c[1], fmaf(az, c[2], c[3])));
        unsigned int u = mono(d);
        if (u < vhi || (u == vhi && (unsigned int)m <= vlo)){
            unsigned int slot = atomicAdd(&cnt[wv], 1u);
            if (slot < CAPW)
                cand[wv][slot] = (((unsigned long long)u) << 12) | (unsigned int)m;
        }
    }
    const unsigned int C = cnt[wv];
    if (C <= CAPW){
        for (unsigned int i = lane; i < C; i += 64){
            unsigned long long mk = cand[wv][i];
            unsigned int rank = 0;
            for (unsigned int j = 0; j < C; j++) rank += (cand[wv][j] < mk) ? 1u : 0u;
            if (rank < K_) knn[(size_t)p*K_ + rank] = (int)(mk & 0xFFFull);
        }
    } else {
        unsigned long long last = 0ull;
        for (int it = 0; it < K_; it++){
            unsigned long long cm = ~0ull;
            #pragma unroll 4
            for (int i = 0; i < 64; i++){
                const int m = i*64 + lane;
                f32x4 c = pb[m];
                float d = fmaf(ax, c[0], fmaf(ay, c[1], fmaf(az, c[2], c[3])));
                unsigned long long key = (((unsigned long long)mono(d)) << 12) | (unsigned int)m;
                if (key > last && key < cm) cm = key;
            }
            #pragma unroll
            for (int off = 32; off; off >>= 1){
                unsigned long long o = __shfl_xor(cm, off, 64);
                cm = o < cm ? o : cm;
            }
            if (lane == 0) knn[(size_t)p*K_ + it] = (int)(cm & 0xFFFull);
            last = cm;
        }
    }
}

// ---------------- MFMA GEMM with K-step register prefetch pipeline --------------
// MODE 0: bias by 256-col range (e0|e1|e2) -> bf16 Y
// MODE 1: *scale(bn)+shift, relu -> bf16 Y
// MODE 2: +bias(e0) + residual featA, write fp32 out transposed (B,C,N)
template<int MODE>
__global__ __launch_bounds__(256) void k_gemm(
    const unsigned short* __restrict__ X, int ldx,
    const unsigned short* __restrict__ W, int Kin,
    const float* __restrict__ e0, const float* __restrict__ e1, const float* __restrict__ e2,
    unsigned short* __restrict__ Y, int ldy,
    const float* __restrict__ resid, float* __restrict__ out)
{
    const int wid = threadIdx.x >> 6, lane = threadIdx.x & 63;
    const int lr = lane & 15, lg = lane >> 4;
    const int mw = blockIdx.x * 128 + wid * 32;
    const int cn = blockIdx.y * 64;
    f32x4 acc[2][4] = {};
    const unsigned short* xr0 = X + (size_t)(mw + lr) * ldx + lg*8;
    const unsigned short* xr1 = xr0 + (size_t)16 * ldx;
    const unsigned short* wr0 = W + (size_t)(cn + lr) * Kin + lg*8;
    bf16x8 a0 = *(const bf16x8*)(xr0);
    bf16x8 a1 = *(const bf16x8*)(xr1);
    bf16x8 b0 = *(const bf16x8*)(wr0);
    bf16x8 b1 = *(const bf16x8*)(wr0 + (size_t)16*Kin);
    bf16x8 b2 = *(const bf16x8*)(wr0 + (size_t)32*Kin);
    bf16x8 b3 = *(const bf16x8*)(wr0 + (size_t)48*Kin);
    for (int k0 = 0; k0 < Kin; k0 += 32){
        bf16x8 na0 = a0, na1 = a1, nb0 = b0, nb1 = b1, nb2 = b2, nb3 = b3;
        const int k = k0 + 32;
        if (k < Kin){
            na0 = *(const bf16x8*)(xr0 + k);
            na1 = *(const bf16x8*)(xr1 + k);
            nb0 = *(const bf16x8*)(wr0 + k);
            nb1 = *(const bf16x8*)(wr0 + (size_t)16*Kin + k);
            nb2 = *(const bf16x8*)(wr0 + (size_t)32*Kin + k);
            nb3 = *(const bf16x8*)(wr0 + (size_t)48*Kin + k);
        }
        acc[0][0] = __builtin_amdgcn_mfma_f32_16x16x32_bf16(a0, b0, acc[0][0], 0, 0, 0);
        acc[1][0] = __builtin_amdgcn_mfma_f32_16x16x32_bf16(a1, b0, acc[1][0], 0, 0, 0);
        acc[0][1] = __builtin_amdgcn_mfma_f32_16x16x32_bf16(a0, b1, acc[0][1], 0, 0, 0);
        acc[1][1] = __builtin_amdgcn_mfma_f32_16x16x32_bf16(a1, b1, acc[1][1], 0, 0, 0);
        acc[0][2] = __builtin_amdgcn_mfma_f32_16x16x32_bf16(a0, b2, acc[0][2], 0, 0, 0);
        acc[1][2] = __builtin_amdgcn_mfma_f32_16x16x32_bf16(a1, b2, acc[1][2], 0, 0, 0);
        acc[0][3] = __builtin_amdgcn_mfma_f32_16x16x32_bf16(a0, b3, acc[0][3], 0, 0, 0);
        acc[1][3] = __builtin_amdgcn_mfma_f32_16x16x32_bf16(a1, b3, acc[1][3], 0, 0, 0);
        a0 = na0; a1 = na1; b0 = nb0; b1 = nb1; b2 = nb2; b3 = nb3;
    }
    #pragma unroll
    for (int mi = 0; mi < 2; mi++){
        const int pbase = mw + mi*16 + lg*4;
        #pragma unroll
        for (int ni = 0; ni < 4; ni++){
            const int o = cn + ni*16 + lr;
            if (MODE == 0){
                const float* bp = (o < 256) ? e0 : ((o < 512) ? e1 : e2);
                float bias = bp[o & 255];
                #pragma unroll
                for (int r = 0; r < 4; r++)
                    Y[(size_t)(pbase + r)*ldy + o] = f2bf(acc[mi][ni][r] + bias);
            } else if (MODE == 1){
                float sc = e0[o] * 0.9999950000374997f;   // rsqrt(1+1e-5)*bn_g
                float sh = e1[o];
                #pragma unroll
                for (int r = 0; r < 4; r++){
                    float vv = fmaf(acc[mi][ni][r], sc, sh);
                    Y[(size_t)(pbase + r)*ldy + o] = f2bf(fmaxf(vv, 0.f));
                }
            } else {
                float bias = e0[o];
                const int b = pbase >> 12, nn = pbase & 4095;
                const size_t adr = ((size_t)b*C_ + o)*N_ + nn;
                f32x4 rv = *(const f32x4*)(resid + adr);
                f32x4 ov;
                #pragma unroll
                for (int r = 0; r < 4; r++) ov[r] = acc[mi][ni][r] + bias + rv[r];
                *(f32x4*)(out + adr) = ov;
            }
        }
    }
}

// ---------------- dual-path neighbor attention: 4 waves per point (head pairs) ----
// QQ: (8192,512) cols 0-255=q_s, 256-511=q_d ; KVD: (8192,768) = k_s|v|k_d
// Block = 256 thr = 4 waves = 1 point; wave wq handles heads {2wq, 2wq+1} (64 dims).
// Waves fully independent until the single LN-combine barrier.
__global__ __launch_bounds__(256) void k_attn(
    const unsigned short* __restrict__ QQ, const unsigned short* __restrict__ KVD,
    const int* __restrict__ KNN,
    const float* __restrict__ lnsw, const float* __restrict__ lnsb,
    const float* __restrict__ lndw, const float* __restrict__ lndb,
    unsigned short* __restrict__ F)
{
    __shared__ float q_l[4][2][64];      // [wq][sim/dis][dim-in-quarter]
    __shared__ float w_l[4][2][2][32];   // [wq][path][hh][k]
    __shared__ int   idx_l[4][32];
    __shared__ float part_l[4][4];

    const int tid = threadIdx.x;
    const int wq = tid >> 6, lane = tid & 63;
    const int p = ((blockIdx.x & 1) << 12) | (blockIdx.x >> 1);  // parity -> batch -> XCD group
    const int b = p >> 12;

    // stage this wave's q quarter + its own copy of knn ids (wave-local, no barrier)
    {
        const unsigned short* qrow = QQ + (size_t)p*512 + wq*64;
        q_l[wq][0][lane] = bf2f(qrow[lane]);
        q_l[wq][1][lane] = bf2f(qrow[256 + lane]);
        if (lane < 32) idx_l[wq][lane] = KNN[(size_t)p*K_ + lane];
    }

    const int hh = lane >> 5, kk = lane & 31;
    const int h = wq*2 + hh;
    {
        const int nbr = idx_l[wq][kk];
        const unsigned short* rowb = KVD + (size_t)((b<<12) + nbr)*768;
        const bf16x8* kr = (const bf16x8*)(rowb + h*32);
        const bf16x8* dr = (const bf16x8*)(rowb + 512 + h*32);
        bf16x8 kx[4], dx[4];
        #pragma unroll
        for (int c = 0; c < 4; c++){ kx[c] = kr[c]; dx[c] = dr[c]; }
        const float* qs = &q_l[wq][0][hh*32];
        const float* qd = &q_l[wq][1][hh*32];
        float s = 0.f, dd = 0.f;
        #pragma unroll
        for (int c = 0; c < 4; c++){
            #pragma unroll
            for (int e = 0; e < 8; e++){
                const int d = c*8 + e;
                s = fmaf(qs[d], bf2f((unsigned short)kx[c][e]), s);
                float df = qd[d] - bf2f((unsigned short)dx[c][e]);
                dd = fmaf(df, df, dd);
            }
        }
        float sim = s * 0.17677669529663687f;   // 1/sqrt(32)
        float dist = sqrtf(dd);
        float m1 = sim, m2 = dist;
        #pragma unroll
        for (int off = 1; off < 32; off <<= 1){
            m1 = fmaxf(m1, __shfl_xor(m1, off, 64));
            m2 = fmaxf(m2, __shfl_xor(m2, off, 64));
        }
        float e1v = __expf(sim - m1);
        float e2v = __expf(dist - m2);
        float s1 = e1v, s2 = e2v;
        #pragma unroll
        for (int off = 1; off < 32; off <<= 1){
            s1 += __shfl_xor(s1, off, 64);
            s2 += __shfl_xor(s2, off, 64);
        }
        w_l[wq][0][hh][kk] = e1v / s1;
        w_l[wq][1][hh][kk] = e2v / s2;
    }

    // PV: lane = (tq = lane>>3 row-octet, c = lane&7 chunk of 8 dims within quarter)
    const int tq = lane >> 3, c = lane & 7;
    const int hhl = c >> 2;
    float cs[8] = {0,0,0,0,0,0,0,0}, cd[8] = {0,0,0,0,0,0,0,0};
    {
        const unsigned short* vbase = KVD + 256 + wq*64 + c*8;
        int t = tq;
        int nbr = idx_l[wq][t];
        bf16x8 cur = *(const bf16x8*)(vbase + (size_t)((b<<12) + nbr)*768);
        #pragma unroll
        for (int i = 0; i < 4; i++){
            bf16x8 nxt = cur;
            if (i < 3){
                int nn = idx_l[wq][t + 8];
                nxt = *(const bf16x8*)(vbase + (size_t)((b<<12) + nn)*768);
            }
            const float wsv = w_l[wq][0][hhl][t];
            const float wdv = w_l[wq][1][hhl][t];
            #pragma unroll
            for (int e = 0; e < 8; e++){
                float vf = bf2f((unsigned short)cur[e]);
                cs[e] = fmaf(wsv, vf, cs[e]);
                cd[e] = fmaf(wdv, vf, cd[e]);
            }
            cur = nxt; t += 8;
        }
    }
    // reduce across the 8 row-octets (xor 8,16,32)
    #pragma unroll
    for (int e = 0; e < 8; e++){
        cs[e] += __shfl_xor(cs[e], 8, 64);
        cs[e] += __shfl_xor(cs[e], 16, 64);
        cs[e] += __shfl_xor(cs[e], 32, 64);
        cd[e] += __shfl_xor(cd[e], 8, 64);
        cd[e] += __shfl_xor(cd[e], 16, 64);
        cd[e] += __shfl_xor(cd[e], 32, 64);
    }
    // quarter (64-dim) LN partials: per-lane chunk sum, then xor 1,2,4 across chunks
    float s1 = 0.f, q1 = 0.f, s2 = 0.f, q2 = 0.f;
    #pragma unroll
    for (int e = 0; e < 8; e++){
        s1 += cs[e]; q1 = fmaf(cs[e], cs[e], q1);
        s2 += cd[e]; q2 = fmaf(cd[e], cd[e], q2);
    }
    #pragma unroll
    for (int off = 1; off < 8; off <<= 1){
        s1 += __shfl_xor(s1, off, 64); q1 += __shfl_xor(q1, off, 64);
        s2 += __shfl_xor(s2, off, 64); q2 += __shfl_xor(q2, off, 64);
    }
    if (lane == 0){
        part_l[wq][0] = s1; part_l[wq][1] = q1;
        part_l[wq][2] = s2; part_l[wq][3] = q2;
    }
    __syncthreads();
    const float S1 = part_l[0][0]+part_l[1][0]+part_l[2][0]+part_l[3][0];
    const float Q1 = part_l[0][1]+part_l[1][1]+part_l[2][1]+part_l[3][1];
    const float S2 = part_l[0][2]+part_l[1][2]+part_l[2][2]+part_l[3][2];
    const float Q2 = part_l[0][3]+part_l[1][3]+part_l[2][3]+part_l[3][3];
    const float m1 = S1*(1.f/256.f), m2 = S2*(1.f/256.f);
    const float r1 = rsqrtf(Q1*(1.f/256.f) - m1*m1 + 1e-5f);
    const float r2 = rsqrtf(Q2*(1.f/256.f) - m2*m2 + 1e-5f);

    if (tq == 0){
        bf16x8 ob;
        #pragma unroll
        for (int e = 0; e < 8; e++){
            const int cg = wq*64 + c*8 + e;
            ob[e] = (short)f2bf((cs[e]-m1)*r1*lnsw[cg] + lnsb[cg]);
        }
        *(bf16x8*)(F + (size_t)p*768 + 256 + wq*64 + c*8) = ob;
    } else if (tq == 1){
        bf16x8 ob;
        #pragma unroll
        for (int e = 0; e < 8; e++){
            const int cg = wq*64 + c*8 + e;
            ob[e] = (short)f2bf((cd[e]-m2)*r2*lndw[cg] + lndb[cg]);
        }
        *(bf16x8*)(F + (size_t)p*768 + 512 + wq*64 + c*8) = ob;
    }
}

extern "C" void kernel_launch(void* const* d_in, const int* in_sizes, int n_in,
                              void* d_out, int out_size, void* d_ws, size_t ws_size,
                              hipStream_t stream)
{
    const float* xyzA   = (const float*)d_in[0];
    const float* xyzB   = (const float*)d_in[1];
    const float* featA  = (const float*)d_in[2];
    const float* featB  = (const float*)d_in[3];
    const float* ln_in_w= (const float*)d_in[4];
    const float* ln_in_b= (const float*)d_in[5];
    const float* wq  = (const float*)d_in[6];
    const float* bq  = (const float*)d_in[7];
    const float* wk  = (const float*)d_in[8];
    const float* bk  = (const float*)d_in[9];
    const float* wv  = (const float*)d_in[10];
    const float* bv  = (const float*)d_in[11];
    const float* wqd = (const float*)d_in[12];
    const float* bqd = (const float*)d_in[13];
    const float* wkd = (const float*)d_in[14];
    const float* bkd = (const float*)d_in[15];
    const float* lnsw = (const float*)d_in[16];
    const float* lnsb = (const float*)d_in[17];
    const float* lndw = (const float*)d_in[18];
    const float* lndb = (const float*)d_in[19];
    const float* fw1 = (const float*)d_in[20];
    const float* bng = (const float*)d_in[21];
    const float* bnb = (const float*)d_in[22];
    const float* fw2 = (const float*)d_in[23];
    const float* fb2 = (const float*)d_in[24];
    float* out = (float*)d_out;
    char* ws = (char*)d_ws;

    unsigned short* F    = (unsigned short*)(ws + 0);          // 8192*768 bf16
    unsigned short* XBT  = (unsigned short*)(ws + 12582912);   // 8192*256
    unsigned short* QQ   = (unsigned short*)(ws + 16777216);   // 8192*512
    unsigned short* KVD  = (unsigned short*)(ws + 25165824);   // 8192*768
    unsigned short* Y1   = (unsigned short*)(ws + 37748736);   // 8192*512 (GEMM) ; PB (knn, earlier)
    f32x4*          PB   = (f32x4*)(ws + 37748736);            // 8192*16B, dead before fus1
    int*            KNNi = (int*)(ws + 46137344);              // 8192*32
    unsigned short* Wb   = (unsigned short*)(ws + 47251456);   // 851968 bf16
    unsigned short* WQcat = Wb;                // 512x256
    unsigned short* WKVD  = Wb + 131072;       // 768x256
    unsigned short* W1b   = Wb + 327680;       // 512x768
    unsigned short* W2b   = Wb + 720896;       // 256x512

    k_cvt_all<<<3328, 256, 0, stream>>>(wq, wqd, wk, wv, wkd, fw1, fw2, Wb);
    k_prep<<<32, 256, 0, stream>>>(xyzB, PB);

    k_lnt<<<256, 256, 0, stream>>>(featA, ln_in_w, ln_in_b, F);
    k_transpose<<<dim3(64,4,2), 256, 0, stream>>>(featB, XBT);
    k_knn<<<2048, 256, 0, stream>>>(xyzA, PB, KNNi);

    k_gemm<0><<<dim3(64,8), 256, 0, stream>>>(F,   768, WQcat, 256, bq, bqd, nullptr, QQ, 512, nullptr, nullptr);
    k_gemm<0><<<dim3(64,12), 256, 0, stream>>>(XBT, 256, WKVD, 256, bk, bv, bkd, KVD, 768, nullptr, nullptr);

    k_attn<<<8192, 256, 0, stream>>>(QQ, KVD, KNNi, lnsw, lnsb, lndw, lndb, F);

    k_gemm<1><<<dim3(64,8), 256, 0, stream>>>(F,  768, W1b, 768, bng, bnb, nullptr, Y1, 512, nullptr, nullptr);
    k_gemm<2><<<dim3(64,4), 256, 0, stream>>>(Y1, 512, W2b, 512, fb2, nullptr, nullptr, nullptr, 0, featA, out);
}